// Round 8
// baseline (260.588 us; speedup 1.0000x reference)
//
#include <hip/hip_runtime.h>
#include <hip/hip_bf16.h>
#include <math.h>

// ---------------------------------------------------------------------------
// ScatterSelfAttention, R15 (gemm2 absorbed into attn tail):
//  - R13/R14 kept: bucket CSR, gemm1+scatter fusion, attn layout B + 2-stage
//    ping-pong (attn pinned ~80us by random-gather throughput; 3 structures
//    identical -> loop done).
//  - NEW: attn blocks = 512 thr / 8 nodes. After per-node reduce, agg is
//    packed bf16 into a 16x136 LDS tile (rows 8..15 zero), one barrier, then
//    8 waves run a cooperative 16x128x128 MFMA mini-GEMM (wave w owns cols
//    w*16..+15; B-frags coalesced from global WoT, L2-hot 32KB; A-frags from
//    LDS). Numerically identical to gemm2 (same bf16 agg quantization).
//  - gemm2 launch + aggb buffer (25.6MB round trip) deleted.
//  3 graph nodes: prep, gemm1+scatter, attn(+out).
// ---------------------------------------------------------------------------

typedef __bf16 bf16x8 __attribute__((ext_vector_type(8)));
typedef float  f32x4  __attribute__((ext_vector_type(4)));

__device__ __forceinline__ ushort f32_to_bf16(float f) {
    uint u = __float_as_uint(f);
    u += 0x7FFF + ((u >> 16) & 1);          // RNE
    return (ushort)(u >> 16);
}
__device__ __forceinline__ uint pack_bf16x2(float a, float b) {
    return (uint)f32_to_bf16(a) | ((uint)f32_to_bf16(b) << 16);
}
__device__ __forceinline__ float bf_lo(uint w) { return __uint_as_float(w << 16); }
__device__ __forceinline__ float bf_hi(uint w) { return __uint_as_float(w & 0xFFFF0000u); }

// C[M, NT*128] = A[M,128] @ Bt[NT*128,128]^T + bias.
// A_FP32: A read as fp32, converted to bf16 during LDS staging.
// Each block owns 128 rows and loops NT col-tiles (A staged once).
// Optional fused hist+scatter tail (independent work, overlaps across blocks).
template<int LDC, bool OUT_BF16, bool A_FP32, int NT>
__global__ __launch_bounds__(256) void gemm_mfma(
    const void* __restrict__ Av, const ushort* __restrict__ Bt,
    const float* __restrict__ bias, void* __restrict__ Cv, int M,
    const int* __restrict__ dst, const int* __restrict__ srcs,
    int* __restrict__ cnt, int2* __restrict__ pairs, int E)
{
    __shared__ uint4 As4[2048];   // 128 rows x 16 bf16x8 cells, XOR-swizzled
    __shared__ uint4 Bs4[2048];
    const int tid  = threadIdx.x;
    const int wave = tid >> 6;
    const int lane = tid & 63;
    const int qd   = lane >> 4;
    const int ln   = lane & 15;
    const int rowBase = blockIdx.x * 128;

    if (A_FP32) {
        const float4* gA = (const float4*)((const float*)Av + (size_t)rowBase * 128);
        #pragma unroll
        for (int i = 0; i < 16; ++i) {
            int c32 = tid + i * 256;
            int r   = c32 >> 5;
            float4 v = make_float4(0.f, 0.f, 0.f, 0.f);
            if (rowBase + r < M) v = gA[c32];
            ushort4 hh;
            hh.x = f32_to_bf16(v.x); hh.y = f32_to_bf16(v.y);
            hh.z = f32_to_bf16(v.z); hh.w = f32_to_bf16(v.w);
            int c16 = c32 >> 1;
            int lc  = (c16 & ~15) | ((c16 ^ (c16 >> 4)) & 15);
            ((ushort4*)As4)[lc * 2 + (c32 & 1)] = hh;
        }
    } else {
        const uint4* gA = (const uint4*)((const ushort*)Av + (size_t)rowBase * 128);
        #pragma unroll
        for (int i = 0; i < 8; ++i) {
            int c  = tid + i * 256;
            int lc = (c & ~15) | ((c ^ (c >> 4)) & 15);
            As4[lc] = gA[c];
        }
    }

    #pragma unroll
    for (int by = 0; by < NT; ++by) {
        const int colBase = by * 128;
        if (by > 0) __syncthreads();       // all waves done reading Bs
        const uint4* gB = (const uint4*)(Bt + (size_t)colBase * 128);
        #pragma unroll
        for (int i = 0; i < 8; ++i) {
            int c  = tid + i * 256;
            int lc = (c & ~15) | ((c ^ (c >> 4)) & 15);
            Bs4[lc] = gB[c];
        }
        __syncthreads();

        f32x4 acc[2][8];
        #pragma unroll
        for (int i = 0; i < 2; ++i)
            #pragma unroll
            for (int j = 0; j < 8; ++j)
                acc[i][j] = (f32x4){0.f, 0.f, 0.f, 0.f};

        const int m0 = wave * 32;
        #pragma unroll
        for (int ks = 0; ks < 4; ++ks) {
            const int kc = ks * 4 + qd;
            bf16x8 a0 = *((const bf16x8*)&As4[(m0 +      ln) * 16 + (kc ^ ln)]);
            bf16x8 a1 = *((const bf16x8*)&As4[(m0 + 16 + ln) * 16 + (kc ^ ln)]);
            #pragma unroll
            for (int j = 0; j < 8; ++j) {
                bf16x8 b = *((const bf16x8*)&Bs4[(j * 16 + ln) * 16 + (kc ^ ln)]);
                acc[0][j] = __builtin_amdgcn_mfma_f32_16x16x32_bf16(b, a0, acc[0][j], 0, 0, 0);
                acc[1][j] = __builtin_amdgcn_mfma_f32_16x16x32_bf16(b, a1, acc[1][j], 0, 0, 0);
            }
        }

        #pragma unroll
        for (int i = 0; i < 2; ++i) {
            int gr = rowBase + m0 + i * 16 + ln;
            if (gr < M) {
                #pragma unroll
                for (int j = 0; j < 8; ++j) {
                    int coln = colBase + j * 16 + qd * 4;
                    float4 b4 = *((const float4*)(bias + coln));
                    float v0 = acc[i][j][0] + b4.x;
                    float v1 = acc[i][j][1] + b4.y;
                    float v2 = acc[i][j][2] + b4.z;
                    float v3 = acc[i][j][3] + b4.w;
                    if (OUT_BF16) {
                        uint2 o;
                        o.x = pack_bf16x2(v0, v1);
                        o.y = pack_bf16x2(v2, v3);
                        *((uint2*)((ushort*)Cv + (size_t)gr * LDC + coln)) = o;
                    } else {
                        float4 o = make_float4(v0, v1, v2, v3);
                        *((float4*)((float*)Cv + (size_t)gr * LDC + coln)) = o;
                    }
                }
            }
        }
    }

    if (E > 0) {                 // fused hist+scatter (bucket CSR, cap 64)
        const int gsz = gridDim.x * 256;
        for (int e = blockIdx.x * 256 + tid; e < E; e += gsz) {
            int d  = dst[e];
            int rk = atomicAdd(&cnt[d], 1);
            if (rk < 64) pairs[((size_t)d << 6) + rk] = make_int2(srcs[e], e);
        }
    }
}

// Grid-stride prep: zero cnt + build WcatT/bcatI/WoT.
// Cb row (384 cols): [0,128)->Q, [128,256)->K, [256,384)->V (natural order).
__global__ __launch_bounds__(256) void prep_kernel(
    const float* __restrict__ Wq, const float* __restrict__ Wk,
    const float* __restrict__ Wv, const float* __restrict__ bq,
    const float* __restrict__ bk, const float* __restrict__ bv,
    const float* __restrict__ Wo,
    ushort* __restrict__ WcatT, float* __restrict__ bcatI, ushort* __restrict__ WoT,
    int* __restrict__ cnt, int N, int GSZ)
{
    const int gid = blockIdx.x * 256 + threadIdx.x;

    for (int i = gid; i < N; i += GSZ) cnt[i] = 0;

    const int WTOT = 384 * 128 + 384 + 128 * 128;
    for (int idx = gid; idx < WTOT; idx += GSZ) {
        if (idx < 384 * 128) {
            int jj = idx >> 7, k = idx & 127;
            const float* W; int c;
            if (jj < 128)      { W = Wq; c = jj; }
            else if (jj < 256) { W = Wk; c = jj - 128; }
            else               { W = Wv; c = jj - 256; }
            WcatT[idx] = f32_to_bf16(W[k * 128 + c]);
        } else if (idx < 384 * 128 + 384) {
            int jj = idx - 384 * 128;
            float b;
            if (jj < 128)      b = bq[jj];
            else if (jj < 256) b = bk[jj - 128];
            else               b = bv[jj - 256];
            bcatI[jj] = b;
        } else {
            int t = idx - (384 * 128 + 384);
            int n = t >> 7, k = t & 127;
            WoT[t] = f32_to_bf16(Wo[k * 128 + n]);
        }
    }
}

// One wave per node, 8 nodes per 512-thread block.
// Layout B: lane = eg*16 + r, r = h*2 + half. 4 edges (eg) per group;
// each lane owns 8 contiguous dims (half) of head h.
// Bucket CSR: edges of node at pairs[node*64 .. node*64+deg), deg<=64.
// 2-stage ping-pong main loop (R14). Tail: agg packed bf16 into LDS
// (16x136, rows 8..15 zero), barrier, cooperative 16x128x128 MFMA
// mini-GEMM vs WoT (global, L2-hot) -> out fp32 (gemm2 absorbed).
__global__ __launch_bounds__(512) void attn_kernel(
    const ushort* __restrict__ Cb, const int* __restrict__ deg,
    const int2* __restrict__ pairs, const float* __restrict__ att_bias,
    const ushort* __restrict__ WoT, const float* __restrict__ bo,
    float* __restrict__ logits_out, float* __restrict__ out, int N)
{
    __shared__ ushort aggB[16 * 136];   // rows 0..7 = block nodes (bf16), pad rows zero
    const int tid  = threadIdx.x;
    const int wv   = tid >> 6;
    const int lane = tid & 63;
    const int node = blockIdx.x * 8 + wv;
    const int eg   = lane >> 4;        // edge-in-group 0..3
    const int r    = lane & 15;        // h*2 + half
    const int h    = r >> 1;
    const int half = lane & 1;

    for (int i = tid; i < 16 * 136; i += 512) aggB[i] = 0;
    __syncthreads();

    const char* cb = (const char*)Cb;

    if (node < N) {
        uint4 qw = *((const uint4*)(cb + (size_t)node * 768) + r);
        const float q0 = bf_lo(qw.x), q1 = bf_hi(qw.x);
        const float q2 = bf_lo(qw.y), q3 = bf_hi(qw.y);
        const float q4 = bf_lo(qw.z), q5 = bf_hi(qw.z);
        const float q6 = bf_lo(qw.w), q7 = bf_hi(qw.w);

        const int dg = min(deg[node], 64);

        float l = 0.f;
        float a0 = 0.f, a1 = 0.f, a2 = 0.f, a3 = 0.f;
        float a4 = 0.f, a5 = 0.f, a6 = 0.f, a7 = 0.f;

        if (dg > 0) {
            int gidx = (node << 6) + ((lane < dg) ? lane : (dg - 1));
            int2 se = pairs[gidx];                     // coalesced (src, eid)
            int regSrc = se.x;
            int regEid = se.y;

            uint4 kwA, vwA; float bbA; int eidA; bool validA;
            uint4 kwB, vwB; float bbB; int eidB; bool validB = false;

            {   // prologue: load stage A for g = 0
                int idxr = eg;
                validA = idxr < dg;
                int idxc = validA ? idxr : (dg - 1);
                int srcn = __shfl(regSrc, idxc);
                eidA = __shfl(regEid, idxc);
                const char* kv = cb + (size_t)((uint)srcn * 768u);
                kwA = *((const uint4*)(kv + 256) + r);
                vwA = *((const uint4*)(kv + 512) + r);
                bbA = att_bias[eidA * 8 + h];
            }

            for (int g = 0; g < dg; g += 8) {
                if (g + 4 < dg) {                       // load B(g+4)
                    int idxr = g + 4 + eg;
                    validB = idxr < dg;
                    int idxc = validB ? idxr : (dg - 1);
                    int srcn = __shfl(regSrc, idxc);
                    eidB = __shfl(regEid, idxc);
                    const char* kv = cb + (size_t)((uint)srcn * 768u);
                    kwB = *((const uint4*)(kv + 256) + r);
                    vwB = *((const uint4*)(kv + 512) + r);
                    bbB = att_bias[eidB * 8 + h];
                }
                {                                       // compute A(g)
                    float p = q0 * bf_lo(kwA.x) + q1 * bf_hi(kwA.x)
                            + q2 * bf_lo(kwA.y) + q3 * bf_hi(kwA.y)
                            + q4 * bf_lo(kwA.z) + q5 * bf_hi(kwA.z)
                            + q6 * bf_lo(kwA.w) + q7 * bf_hi(kwA.w);
                    p += __shfl_xor(p, 1);
                    float logit = p * 0.25f + bbA;
                    if (validA && half == 0) logits_out[eidA * 8 + h] = logit;
                    float pe = validA ? __expf(logit) : 0.f;
                    l += pe;
                    a0 = fmaf(pe, bf_lo(vwA.x), a0); a1 = fmaf(pe, bf_hi(vwA.x), a1);
                    a2 = fmaf(pe, bf_lo(vwA.y), a2); a3 = fmaf(pe, bf_hi(vwA.y), a3);
                    a4 = fmaf(pe, bf_lo(vwA.z), a4); a5 = fmaf(pe, bf_hi(vwA.z), a5);
                    a6 = fmaf(pe, bf_lo(vwA.w), a6); a7 = fmaf(pe, bf_hi(vwA.w), a7);
                }
                if (g + 8 < dg) {                       // load A(g+8)
                    int idxr = g + 8 + eg;
                    validA = idxr < dg;
                    int idxc = validA ? idxr : (dg - 1);
                    int srcn = __shfl(regSrc, idxc);
                    eidA = __shfl(regEid, idxc);
                    const char* kv = cb + (size_t)((uint)srcn * 768u);
                    kwA = *((const uint4*)(kv + 256) + r);
                    vwA = *((const uint4*)(kv + 512) + r);
                    bbA = att_bias[eidA * 8 + h];
                }
                if (g + 4 < dg) {                       // compute B(g+4)
                    float p = q0 * bf_lo(kwB.x) + q1 * bf_hi(kwB.x)
                            + q2 * bf_lo(kwB.y) + q3 * bf_hi(kwB.y)
                            + q4 * bf_lo(kwB.z) + q5 * bf_hi(kwB.z)
                            + q6 * bf_lo(kwB.w) + q7 * bf_hi(kwB.w);
                    p += __shfl_xor(p, 1);
                    float logit = p * 0.25f + bbB;
                    if (validB && half == 0) logits_out[eidB * 8 + h] = logit;
                    float pe = validB ? __expf(logit) : 0.f;
                    l += pe;
                    a0 = fmaf(pe, bf_lo(vwB.x), a0); a1 = fmaf(pe, bf_hi(vwB.x), a1);
                    a2 = fmaf(pe, bf_lo(vwB.y), a2); a3 = fmaf(pe, bf_hi(vwB.y), a3);
                    a4 = fmaf(pe, bf_lo(vwB.z), a4); a5 = fmaf(pe, bf_hi(vwB.z), a5);
                    a6 = fmaf(pe, bf_lo(vwB.w), a6); a7 = fmaf(pe, bf_hi(vwB.w), a7);
                }
            }
        }

        // reduce across eg lanes (bits 4,5); each eg-lane held a disjoint
        // edge subset, so l/aX become full sums per (h, half) lane.
        #pragma unroll
        for (int m = 16; m <= 32; m <<= 1) {
            l  += __shfl_xor(l, m);
            a0 += __shfl_xor(a0, m); a1 += __shfl_xor(a1, m);
            a2 += __shfl_xor(a2, m); a3 += __shfl_xor(a3, m);
            a4 += __shfl_xor(a4, m); a5 += __shfl_xor(a5, m);
            a6 += __shfl_xor(a6, m); a7 += __shfl_xor(a7, m);
        }
        float inv = (l > 0.f) ? (1.f / l) : 0.f;
        if (eg == 0) {
            uint4 o;
            o.x = pack_bf16x2(a0 * inv, a1 * inv);
            o.y = pack_bf16x2(a2 * inv, a3 * inv);
            o.z = pack_bf16x2(a4 * inv, a5 * inv);
            o.w = pack_bf16x2(a6 * inv, a7 * inv);
            *((uint4*)&aggB[wv * 136 + r * 8]) = o;    // row wv, cols r*8..+7
        }
    }
    __syncthreads();

    // ---- mini-GEMM: out[8 x 128] = aggB(bf16) @ WoT^T + bo (fp32 out) ----
    // Wave wv owns output cols wv*16 .. wv*16+15. Same mfma(b,a) mapping as
    // gemm_mfma: lane ln -> output row ln (node blockIdx*8+ln, ln<8 valid),
    // cols wv*16 + qd*4 .. +3.
    {
        const int qd = lane >> 4;
        const int ln = lane & 15;
        f32x4 acc = (f32x4){0.f, 0.f, 0.f, 0.f};
        const uint4* Wg = (const uint4*)WoT;   // row c (out col) = 16 uint4
        #pragma unroll
        for (int ks = 0; ks < 4; ++ks) {
            const int kc = ks * 4 + qd;
            bf16x8 a = *((const bf16x8*)&aggB[ln * 136 + kc * 8]);
            bf16x8 b = *((const bf16x8*)&Wg[wv * 256 + ln * 16 + ks * 4 + qd]);
            acc = __builtin_amdgcn_mfma_f32_16x16x32_bf16(b, a, acc, 0, 0, 0);
        }
        const int gr = blockIdx.x * 8 + ln;
        if (ln < 8 && gr < N) {
            const int coln = wv * 16 + qd * 4;
            float4 b4 = *((const float4*)(bo + coln));
            float4 o = make_float4(acc[0] + b4.x, acc[1] + b4.y,
                                   acc[2] + b4.z, acc[3] + b4.w);
            *((float4*)(out + (size_t)gr * 128 + coln)) = o;
        }
    }
}

extern "C" void kernel_launch(void* const* d_in, const int* in_sizes, int n_in,
                              void* d_out, int out_size, void* d_ws, size_t ws_size,
                              hipStream_t stream)
{
    const float* x        = (const float*)d_in[0];
    const int*   ei       = (const int*)d_in[1];   // [2,E]: dst row then src row
    const float* att_bias = (const float*)d_in[2];
    const float* Wq = (const float*)d_in[3];  const float* bq = (const float*)d_in[4];
    const float* Wk = (const float*)d_in[5];  const float* bk = (const float*)d_in[6];
    const float* Wv = (const float*)d_in[7];  const float* bv = (const float*)d_in[8];
    const float* Wo = (const float*)d_in[9];  const float* bo = (const float*)d_in[10];

    const int N = in_sizes[0] / 128;
    const int E = in_sizes[1] / 2;

    float* out    = (float*)d_out;               // [N,128]
    float* logits = out + (size_t)N * 128;       // [E,8]

    char* ws = (char*)d_ws;
    size_t o = 0;
    auto alloc = [&](size_t bytes) -> char* {
        char* p = ws + o;
        o = (o + bytes + 255) & ~(size_t)255;
        return p;
    };
    ushort* Cb    = (ushort*)alloc((size_t)N * 384 * 2);   // [Q|K|V] per row
    ushort* WcatT = (ushort*)alloc((size_t)384 * 128 * 2);
    float*  bcatI = (float*)alloc(384 * 4);
    ushort* WoT   = (ushort*)alloc((size_t)128 * 128 * 2);
    int*    cnt   = (int*)alloc((size_t)N * 4);
    int2*   pairs = (int2*)alloc((size_t)N * 64 * 8);      // bucket CSR

    const int MB = (N + 127) / 128;              // 391

    const int PREP_BLOCKS = 512;
    prep_kernel<<<PREP_BLOCKS, 256, 0, stream>>>(
        Wq, Wk, Wv, bq, bk, bv, Wo, WcatT, bcatI, WoT, cnt,
        N, PREP_BLOCKS * 256);

    // QKV projection (A staged once, 3 col-tiles) + fused hist+scatter
    gemm_mfma<384, true, true, 3><<<MB, 256, 0, stream>>>(
        x, WcatT, bcatI, Cb, N, ei, ei + E, cnt, pairs, E);

    // attn + absorbed output GEMM
    attn_kernel<<<(N + 7) / 8, 512, 0, stream>>>(Cb, cnt, pairs, att_bias,
                                                 WoT, bo, logits, out, N);
}

// Round 9
// 251.646 us; speedup vs baseline: 1.0355x; 1.0355x over previous
//
#include <hip/hip_runtime.h>
#include <hip/hip_bf16.h>
#include <math.h>

// ---------------------------------------------------------------------------
// ScatterSelfAttention, R16 (scatter-parallelism isolation):
//  - attn/gemm2: exact R14 split restored (R15's in-attn mini-GEMM was net
//    zero: barrier imbalance over 8 waves ate the launch+aggb savings).
//  - gemm1: grid padded to 1024 blocks. Blocks with rowBase >= M skip the
//    GEMM body (block-uniform branch) and only run the fused hist+scatter
//    tail -> edge-tail parallelism 100K -> 262K threads (8 -> 3 grid-stride
//    iterations of random-line atomic + write). R13 had silently cut this
//    parallelism 8x vs R11's dedicated scatter kernel.
//  4 graph nodes: prep, gemm1(+scatter, padded grid), attn, gemm2.
// ---------------------------------------------------------------------------

typedef __bf16 bf16x8 __attribute__((ext_vector_type(8)));
typedef float  f32x4  __attribute__((ext_vector_type(4)));

__device__ __forceinline__ ushort f32_to_bf16(float f) {
    uint u = __float_as_uint(f);
    u += 0x7FFF + ((u >> 16) & 1);          // RNE
    return (ushort)(u >> 16);
}
__device__ __forceinline__ uint pack_bf16x2(float a, float b) {
    return (uint)f32_to_bf16(a) | ((uint)f32_to_bf16(b) << 16);
}
__device__ __forceinline__ float bf_lo(uint w) { return __uint_as_float(w << 16); }
__device__ __forceinline__ float bf_hi(uint w) { return __uint_as_float(w & 0xFFFF0000u); }

// C[M, NT*128] = A[M,128] @ Bt[NT*128,128]^T + bias.
// A_FP32: A read as fp32, converted to bf16 during LDS staging.
// Blocks with rowBase < M do the GEMM (A staged once, NT col-tiles);
// ALL blocks run the optional fused hist+scatter tail (grid may be padded
// beyond the GEMM tiles purely to parallelize the tail).
template<int LDC, bool OUT_BF16, bool A_FP32, int NT>
__global__ __launch_bounds__(256) void gemm_mfma(
    const void* __restrict__ Av, const ushort* __restrict__ Bt,
    const float* __restrict__ bias, void* __restrict__ Cv, int M,
    const int* __restrict__ dst, const int* __restrict__ srcs,
    int* __restrict__ cnt, int2* __restrict__ pairs, int E)
{
    __shared__ uint4 As4[2048];   // 128 rows x 16 bf16x8 cells, XOR-swizzled
    __shared__ uint4 Bs4[2048];
    const int tid  = threadIdx.x;
    const int wave = tid >> 6;
    const int lane = tid & 63;
    const int qd   = lane >> 4;
    const int ln   = lane & 15;
    const int rowBase = blockIdx.x * 128;

    if (rowBase < M) {                     // block-uniform: GEMM body
        if (A_FP32) {
            const float4* gA = (const float4*)((const float*)Av + (size_t)rowBase * 128);
            #pragma unroll
            for (int i = 0; i < 16; ++i) {
                int c32 = tid + i * 256;
                int r   = c32 >> 5;
                float4 v = make_float4(0.f, 0.f, 0.f, 0.f);
                if (rowBase + r < M) v = gA[c32];
                ushort4 hh;
                hh.x = f32_to_bf16(v.x); hh.y = f32_to_bf16(v.y);
                hh.z = f32_to_bf16(v.z); hh.w = f32_to_bf16(v.w);
                int c16 = c32 >> 1;
                int lc  = (c16 & ~15) | ((c16 ^ (c16 >> 4)) & 15);
                ((ushort4*)As4)[lc * 2 + (c32 & 1)] = hh;
            }
        } else {
            const uint4* gA = (const uint4*)((const ushort*)Av + (size_t)rowBase * 128);
            #pragma unroll
            for (int i = 0; i < 8; ++i) {
                int c  = tid + i * 256;
                int lc = (c & ~15) | ((c ^ (c >> 4)) & 15);
                As4[lc] = gA[c];
            }
        }

        #pragma unroll
        for (int by = 0; by < NT; ++by) {
            const int colBase = by * 128;
            if (by > 0) __syncthreads();       // all waves done reading Bs
            const uint4* gB = (const uint4*)(Bt + (size_t)colBase * 128);
            #pragma unroll
            for (int i = 0; i < 8; ++i) {
                int c  = tid + i * 256;
                int lc = (c & ~15) | ((c ^ (c >> 4)) & 15);
                Bs4[lc] = gB[c];
            }
            __syncthreads();

            f32x4 acc[2][8];
            #pragma unroll
            for (int i = 0; i < 2; ++i)
                #pragma unroll
                for (int j = 0; j < 8; ++j)
                    acc[i][j] = (f32x4){0.f, 0.f, 0.f, 0.f};

            const int m0 = wave * 32;
            #pragma unroll
            for (int ks = 0; ks < 4; ++ks) {
                const int kc = ks * 4 + qd;
                bf16x8 a0 = *((const bf16x8*)&As4[(m0 +      ln) * 16 + (kc ^ ln)]);
                bf16x8 a1 = *((const bf16x8*)&As4[(m0 + 16 + ln) * 16 + (kc ^ ln)]);
                #pragma unroll
                for (int j = 0; j < 8; ++j) {
                    bf16x8 b = *((const bf16x8*)&Bs4[(j * 16 + ln) * 16 + (kc ^ ln)]);
                    acc[0][j] = __builtin_amdgcn_mfma_f32_16x16x32_bf16(b, a0, acc[0][j], 0, 0, 0);
                    acc[1][j] = __builtin_amdgcn_mfma_f32_16x16x32_bf16(b, a1, acc[1][j], 0, 0, 0);
                }
            }

            #pragma unroll
            for (int i = 0; i < 2; ++i) {
                int gr = rowBase + m0 + i * 16 + ln;
                if (gr < M) {
                    #pragma unroll
                    for (int j = 0; j < 8; ++j) {
                        int coln = colBase + j * 16 + qd * 4;
                        float4 b4 = *((const float4*)(bias + coln));
                        float v0 = acc[i][j][0] + b4.x;
                        float v1 = acc[i][j][1] + b4.y;
                        float v2 = acc[i][j][2] + b4.z;
                        float v3 = acc[i][j][3] + b4.w;
                        if (OUT_BF16) {
                            uint2 o;
                            o.x = pack_bf16x2(v0, v1);
                            o.y = pack_bf16x2(v2, v3);
                            *((uint2*)((ushort*)Cv + (size_t)gr * LDC + coln)) = o;
                        } else {
                            float4 o = make_float4(v0, v1, v2, v3);
                            *((float4*)((float*)Cv + (size_t)gr * LDC + coln)) = o;
                        }
                    }
                }
            }
        }
    }

    if (E > 0) {                 // fused hist+scatter (bucket CSR, cap 64)
        const int gsz = gridDim.x * 256;
        for (int e = blockIdx.x * 256 + tid; e < E; e += gsz) {
            int d  = dst[e];
            int rk = atomicAdd(&cnt[d], 1);
            if (rk < 64) pairs[((size_t)d << 6) + rk] = make_int2(srcs[e], e);
        }
    }
}

// Grid-stride prep: zero cnt + build WcatT/bcatI/WoT.
// Cb row (384 cols): [0,128)->Q, [128,256)->K, [256,384)->V (natural order).
__global__ __launch_bounds__(256) void prep_kernel(
    const float* __restrict__ Wq, const float* __restrict__ Wk,
    const float* __restrict__ Wv, const float* __restrict__ bq,
    const float* __restrict__ bk, const float* __restrict__ bv,
    const float* __restrict__ Wo,
    ushort* __restrict__ WcatT, float* __restrict__ bcatI, ushort* __restrict__ WoT,
    int* __restrict__ cnt, int N, int GSZ)
{
    const int gid = blockIdx.x * 256 + threadIdx.x;

    for (int i = gid; i < N; i += GSZ) cnt[i] = 0;

    const int WTOT = 384 * 128 + 384 + 128 * 128;
    for (int idx = gid; idx < WTOT; idx += GSZ) {
        if (idx < 384 * 128) {
            int jj = idx >> 7, k = idx & 127;
            const float* W; int c;
            if (jj < 128)      { W = Wq; c = jj; }
            else if (jj < 256) { W = Wk; c = jj - 128; }
            else               { W = Wv; c = jj - 256; }
            WcatT[idx] = f32_to_bf16(W[k * 128 + c]);
        } else if (idx < 384 * 128 + 384) {
            int jj = idx - 384 * 128;
            float b;
            if (jj < 128)      b = bq[jj];
            else if (jj < 256) b = bk[jj - 128];
            else               b = bv[jj - 256];
            bcatI[jj] = b;
        } else {
            int t = idx - (384 * 128 + 384);
            int n = t >> 7, k = t & 127;
            WoT[t] = f32_to_bf16(Wo[k * 128 + n]);
        }
    }
}

// One wave per node, 4 nodes per 256-thread block.
// Layout B: lane = eg*16 + r, r = h*2 + half. 4 edges (eg) per group;
// each lane owns 8 contiguous dims (half) of head h.
// Bucket CSR: edges of node at pairs[node*64 .. node*64+deg), deg<=64.
// 2-stage ping-pong (A = groups 0,8,16,..; B = groups 4,12,20,..).
__global__ __launch_bounds__(256) void attn_kernel(
    const ushort* __restrict__ Cb, const int* __restrict__ deg,
    const int2* __restrict__ pairs, const float* __restrict__ att_bias,
    float* __restrict__ logits_out, ushort* __restrict__ aggb, int N)
{
    const int wv   = threadIdx.x >> 6;
    const int lane = threadIdx.x & 63;
    const int node = blockIdx.x * 4 + wv;
    if (node >= N) return;
    const int eg   = lane >> 4;        // edge-in-group 0..3
    const int r    = lane & 15;        // h*2 + half
    const int h    = r >> 1;
    const int half = lane & 1;

    const char* cb = (const char*)Cb;

    uint4 qw = *((const uint4*)(cb + (size_t)node * 768) + r);
    const float q0 = bf_lo(qw.x), q1 = bf_hi(qw.x);
    const float q2 = bf_lo(qw.y), q3 = bf_hi(qw.y);
    const float q4 = bf_lo(qw.z), q5 = bf_hi(qw.z);
    const float q6 = bf_lo(qw.w), q7 = bf_hi(qw.w);

    const int dg = min(deg[node], 64);

    float l = 0.f;
    float a0 = 0.f, a1 = 0.f, a2 = 0.f, a3 = 0.f;
    float a4 = 0.f, a5 = 0.f, a6 = 0.f, a7 = 0.f;

    if (dg > 0) {
        int gidx = (node << 6) + ((lane < dg) ? lane : (dg - 1));
        int2 se = pairs[gidx];                         // coalesced (src, eid)
        int regSrc = se.x;
        int regEid = se.y;

        uint4 kwA, vwA; float bbA; int eidA; bool validA;
        uint4 kwB, vwB; float bbB; int eidB; bool validB = false;

        // prologue: load stage A for g = 0
        {
            int idxr = eg;
            validA = idxr < dg;
            int idxc = validA ? idxr : (dg - 1);
            int srcn = __shfl(regSrc, idxc);
            eidA = __shfl(regEid, idxc);
            const char* kv = cb + (size_t)((uint)srcn * 768u);
            kwA = *((const uint4*)(kv + 256) + r);
            vwA = *((const uint4*)(kv + 512) + r);
            bbA = att_bias[eidA * 8 + h];
        }

        for (int g = 0; g < dg; g += 8) {
            if (g + 4 < dg) {                       // load B(g+4)
                int idxr = g + 4 + eg;
                validB = idxr < dg;
                int idxc = validB ? idxr : (dg - 1);
                int srcn = __shfl(regSrc, idxc);
                eidB = __shfl(regEid, idxc);
                const char* kv = cb + (size_t)((uint)srcn * 768u);
                kwB = *((const uint4*)(kv + 256) + r);
                vwB = *((const uint4*)(kv + 512) + r);
                bbB = att_bias[eidB * 8 + h];
            }
            {                                       // compute A(g)
                float p = q0 * bf_lo(kwA.x) + q1 * bf_hi(kwA.x)
                        + q2 * bf_lo(kwA.y) + q3 * bf_hi(kwA.y)
                        + q4 * bf_lo(kwA.z) + q5 * bf_hi(kwA.z)
                        + q6 * bf_lo(kwA.w) + q7 * bf_hi(kwA.w);
                p += __shfl_xor(p, 1);
                float logit = p * 0.25f + bbA;
                if (validA && half == 0) logits_out[eidA * 8 + h] = logit;
                float pe = validA ? __expf(logit) : 0.f;
                l += pe;
                a0 = fmaf(pe, bf_lo(vwA.x), a0); a1 = fmaf(pe, bf_hi(vwA.x), a1);
                a2 = fmaf(pe, bf_lo(vwA.y), a2); a3 = fmaf(pe, bf_hi(vwA.y), a3);
                a4 = fmaf(pe, bf_lo(vwA.z), a4); a5 = fmaf(pe, bf_hi(vwA.z), a5);
                a6 = fmaf(pe, bf_lo(vwA.w), a6); a7 = fmaf(pe, bf_hi(vwA.w), a7);
            }
            if (g + 8 < dg) {                       // load A(g+8)
                int idxr = g + 8 + eg;
                validA = idxr < dg;
                int idxc = validA ? idxr : (dg - 1);
                int srcn = __shfl(regSrc, idxc);
                eidA = __shfl(regEid, idxc);
                const char* kv = cb + (size_t)((uint)srcn * 768u);
                kwA = *((const uint4*)(kv + 256) + r);
                vwA = *((const uint4*)(kv + 512) + r);
                bbA = att_bias[eidA * 8 + h];
            }
            if (g + 4 < dg) {                       // compute B(g+4)
                float p = q0 * bf_lo(kwB.x) + q1 * bf_hi(kwB.x)
                        + q2 * bf_lo(kwB.y) + q3 * bf_hi(kwB.y)
                        + q4 * bf_lo(kwB.z) + q5 * bf_hi(kwB.z)
                        + q6 * bf_lo(kwB.w) + q7 * bf_hi(kwB.w);
                p += __shfl_xor(p, 1);
                float logit = p * 0.25f + bbB;
                if (validB && half == 0) logits_out[eidB * 8 + h] = logit;
                float pe = validB ? __expf(logit) : 0.f;
                l += pe;
                a0 = fmaf(pe, bf_lo(vwB.x), a0); a1 = fmaf(pe, bf_hi(vwB.x), a1);
                a2 = fmaf(pe, bf_lo(vwB.y), a2); a3 = fmaf(pe, bf_hi(vwB.y), a3);
                a4 = fmaf(pe, bf_lo(vwB.z), a4); a5 = fmaf(pe, bf_hi(vwB.z), a5);
                a6 = fmaf(pe, bf_lo(vwB.w), a6); a7 = fmaf(pe, bf_hi(vwB.w), a7);
            }
        }
    }

    // reduce across eg lanes (bits 4,5); each eg-lane held a disjoint
    // edge subset, so l/aX become full sums per (h, half) lane.
    #pragma unroll
    for (int m = 16; m <= 32; m <<= 1) {
        l  += __shfl_xor(l, m);
        a0 += __shfl_xor(a0, m); a1 += __shfl_xor(a1, m);
        a2 += __shfl_xor(a2, m); a3 += __shfl_xor(a3, m);
        a4 += __shfl_xor(a4, m); a5 += __shfl_xor(a5, m);
        a6 += __shfl_xor(a6, m); a7 += __shfl_xor(a7, m);
    }
    float inv = (l > 0.f) ? (1.f / l) : 0.f;
    if (eg == 0) {
        uint4 o;
        o.x = pack_bf16x2(a0 * inv, a1 * inv);
        o.y = pack_bf16x2(a2 * inv, a3 * inv);
        o.z = pack_bf16x2(a4 * inv, a5 * inv);
        o.w = pack_bf16x2(a6 * inv, a7 * inv);
        ((uint4*)(aggb + (size_t)node * 128))[r] = o;   // cols r*8..r*8+7
    }
}

extern "C" void kernel_launch(void* const* d_in, const int* in_sizes, int n_in,
                              void* d_out, int out_size, void* d_ws, size_t ws_size,
                              hipStream_t stream)
{
    const float* x        = (const float*)d_in[0];
    const int*   ei       = (const int*)d_in[1];   // [2,E]: dst row then src row
    const float* att_bias = (const float*)d_in[2];
    const float* Wq = (const float*)d_in[3];  const float* bq = (const float*)d_in[4];
    const float* Wk = (const float*)d_in[5];  const float* bk = (const float*)d_in[6];
    const float* Wv = (const float*)d_in[7];  const float* bv = (const float*)d_in[8];
    const float* Wo = (const float*)d_in[9];  const float* bo = (const float*)d_in[10];

    const int N = in_sizes[0] / 128;
    const int E = in_sizes[1] / 2;

    float* out    = (float*)d_out;               // [N,128]
    float* logits = out + (size_t)N * 128;       // [E,8]

    char* ws = (char*)d_ws;
    size_t o = 0;
    auto alloc = [&](size_t bytes) -> char* {
        char* p = ws + o;
        o = (o + bytes + 255) & ~(size_t)255;
        return p;
    };
    const int Mpad = ((N + 127) / 128) * 128;
    ushort* Cb    = (ushort*)alloc((size_t)N * 384 * 2);   // [Q|K|V] per row
    ushort* aggb  = (ushort*)alloc((size_t)Mpad * 128 * 2);
    ushort* WcatT = (ushort*)alloc((size_t)384 * 128 * 2);
    float*  bcatI = (float*)alloc(384 * 4);
    ushort* WoT   = (ushort*)alloc((size_t)128 * 128 * 2);
    int*    cnt   = (int*)alloc((size_t)N * 4);
    int2*   pairs = (int2*)alloc((size_t)N * 64 * 8);      // bucket CSR

    const int MB = (N + 127) / 128;              // 391
    const int GEMM1_BLOCKS = 1024;               // extra blocks -> scatter tail

    const int PREP_BLOCKS = 512;
    prep_kernel<<<PREP_BLOCKS, 256, 0, stream>>>(
        Wq, Wk, Wv, bq, bk, bv, Wo, WcatT, bcatI, WoT, cnt,
        N, PREP_BLOCKS * 256);

    // QKV projection (blocks < MB) + fused hist+scatter (all 1024 blocks)
    gemm_mfma<384, true, true, 3><<<GEMM1_BLOCKS, 256, 0, stream>>>(
        x, WcatT, bcatI, Cb, N, ei, ei + E, cnt, pairs, E);

    attn_kernel<<<(N + 3) / 4, 256, 0, stream>>>(Cb, cnt, pairs, att_bias,
                                                 logits, aggb, N);

    gemm_mfma<128, false, false, 1><<<MB, 256, 0, stream>>>(
        aggb, WoT, bo, out, N, nullptr, nullptr, nullptr, nullptr, 0);
}

// Round 10
// 239.842 us; speedup vs baseline: 1.0865x; 1.0492x over previous
//
#include <hip/hip_runtime.h>
#include <hip/hip_bf16.h>
#include <math.h>

// ---------------------------------------------------------------------------
// ScatterSelfAttention, R17 (V in fp8):
//  - R16 kept: bucket CSR, gemm1 padded grid (1024 blocks) + fused
//    hist/scatter tail, attn layout B + 2-stage ping-pong, split gemm2.
//  - NEW: V stored fp8 e4m3 in Cb (row = [Q 256B bf16 | K 256B bf16 |
//    V 128B fp8] = 640B, was 768B). KV gather 512->384 B/edge (-25%).
//    Logits path (Q,K bf16) untouched -> logits bit-identical to R16.
//    V encode: v_cvt_pk_fp8_f32 in gemm1 epilogue; decode:
//    v_cvt_pk_f32_fp8 in attn (4 VALU ops/edge, VALU at 33% has headroom).
//  4 graph nodes: prep, gemm1(+scatter), attn, gemm2.
// ---------------------------------------------------------------------------

typedef __bf16 bf16x8 __attribute__((ext_vector_type(8)));
typedef float  f32x4  __attribute__((ext_vector_type(4)));
typedef float  f32x2  __attribute__((ext_vector_type(2)));

__device__ __forceinline__ ushort f32_to_bf16(float f) {
    uint u = __float_as_uint(f);
    u += 0x7FFF + ((u >> 16) & 1);          // RNE
    return (ushort)(u >> 16);
}
__device__ __forceinline__ uint pack_bf16x2(float a, float b) {
    return (uint)f32_to_bf16(a) | ((uint)f32_to_bf16(b) << 16);
}
__device__ __forceinline__ float bf_lo(uint w) { return __uint_as_float(w << 16); }
__device__ __forceinline__ float bf_hi(uint w) { return __uint_as_float(w & 0xFFFF0000u); }

// MODE 0: gemm1 -> Cb rows of 640B: [Q 256B bf16 | K 256B bf16 | V 128B fp8]
//         (col-tile by: 0=Q, 1=K, 2=V). A is fp32 x, converted at staging.
// MODE 1: gemm2 -> fp32 out rows of 128 floats. A is bf16 aggb.
// Blocks with rowBase < M do the GEMM; ALL blocks run the optional fused
// hist+scatter tail (grid may be padded beyond the GEMM tiles).
template<int MODE, int NT>
__global__ __launch_bounds__(256) void gemm_mfma(
    const void* __restrict__ Av, const ushort* __restrict__ Bt,
    const float* __restrict__ bias, void* __restrict__ Cv, int M,
    const int* __restrict__ dst, const int* __restrict__ srcs,
    int* __restrict__ cnt, int2* __restrict__ pairs, int E)
{
    __shared__ uint4 As4[2048];   // 128 rows x 16 bf16x8 cells, XOR-swizzled
    __shared__ uint4 Bs4[2048];
    const int tid  = threadIdx.x;
    const int wave = tid >> 6;
    const int lane = tid & 63;
    const int qd   = lane >> 4;
    const int ln   = lane & 15;
    const int rowBase = blockIdx.x * 128;

    if (rowBase < M) {                     // block-uniform: GEMM body
        if (MODE == 0) {                   // A = x fp32, convert to bf16
            const float4* gA = (const float4*)((const float*)Av + (size_t)rowBase * 128);
            #pragma unroll
            for (int i = 0; i < 16; ++i) {
                int c32 = tid + i * 256;
                int r   = c32 >> 5;
                float4 v = make_float4(0.f, 0.f, 0.f, 0.f);
                if (rowBase + r < M) v = gA[c32];
                ushort4 hh;
                hh.x = f32_to_bf16(v.x); hh.y = f32_to_bf16(v.y);
                hh.z = f32_to_bf16(v.z); hh.w = f32_to_bf16(v.w);
                int c16 = c32 >> 1;
                int lc  = (c16 & ~15) | ((c16 ^ (c16 >> 4)) & 15);
                ((ushort4*)As4)[lc * 2 + (c32 & 1)] = hh;
            }
        } else {                           // A = aggb bf16
            const uint4* gA = (const uint4*)((const ushort*)Av + (size_t)rowBase * 128);
            #pragma unroll
            for (int i = 0; i < 8; ++i) {
                int c  = tid + i * 256;
                int lc = (c & ~15) | ((c ^ (c >> 4)) & 15);
                As4[lc] = gA[c];
            }
        }

        #pragma unroll
        for (int by = 0; by < NT; ++by) {
            const int colBase = by * 128;
            if (by > 0) __syncthreads();       // all waves done reading Bs
            const uint4* gB = (const uint4*)(Bt + (size_t)colBase * 128);
            #pragma unroll
            for (int i = 0; i < 8; ++i) {
                int c  = tid + i * 256;
                int lc = (c & ~15) | ((c ^ (c >> 4)) & 15);
                Bs4[lc] = gB[c];
            }
            __syncthreads();

            f32x4 acc[2][8];
            #pragma unroll
            for (int i = 0; i < 2; ++i)
                #pragma unroll
                for (int j = 0; j < 8; ++j)
                    acc[i][j] = (f32x4){0.f, 0.f, 0.f, 0.f};

            const int m0 = wave * 32;
            #pragma unroll
            for (int ks = 0; ks < 4; ++ks) {
                const int kc = ks * 4 + qd;
                bf16x8 a0 = *((const bf16x8*)&As4[(m0 +      ln) * 16 + (kc ^ ln)]);
                bf16x8 a1 = *((const bf16x8*)&As4[(m0 + 16 + ln) * 16 + (kc ^ ln)]);
                #pragma unroll
                for (int j = 0; j < 8; ++j) {
                    bf16x8 b = *((const bf16x8*)&Bs4[(j * 16 + ln) * 16 + (kc ^ ln)]);
                    acc[0][j] = __builtin_amdgcn_mfma_f32_16x16x32_bf16(b, a0, acc[0][j], 0, 0, 0);
                    acc[1][j] = __builtin_amdgcn_mfma_f32_16x16x32_bf16(b, a1, acc[1][j], 0, 0, 0);
                }
            }

            #pragma unroll
            for (int i = 0; i < 2; ++i) {
                int gr = rowBase + m0 + i * 16 + ln;
                if (gr < M) {
                    #pragma unroll
                    for (int j = 0; j < 8; ++j) {
                        int coln = colBase + j * 16 + qd * 4;  // global col
                        float4 b4 = *((const float4*)(bias + coln));
                        float v0 = acc[i][j][0] + b4.x;
                        float v1 = acc[i][j][1] + b4.y;
                        float v2 = acc[i][j][2] + b4.z;
                        float v3 = acc[i][j][3] + b4.w;
                        if (MODE == 0) {
                            int cloc = j * 16 + qd * 4;        // col within tile
                            char* row = (char*)Cv + (size_t)gr * 640;
                            if (by < 2) {                      // Q / K bf16
                                uint2 o;
                                o.x = pack_bf16x2(v0, v1);
                                o.y = pack_bf16x2(v2, v3);
                                *((uint2*)(row + by * 256 + cloc * 2)) = o;
                            } else {                           // V fp8 e4m3
                                int w8 = 0;
                                w8 = __builtin_amdgcn_cvt_pk_fp8_f32(v0, v1, w8, false);
                                w8 = __builtin_amdgcn_cvt_pk_fp8_f32(v2, v3, w8, true);
                                *((uint*)(row + 512 + cloc)) = (uint)w8;
                            }
                        } else {
                            float4 o = make_float4(v0, v1, v2, v3);
                            *((float4*)((float*)Cv + (size_t)gr * 128 + coln)) = o;
                        }
                    }
                }
            }
        }
    }

    if (E > 0) {                 // fused hist+scatter (bucket CSR, cap 64)
        const int gsz = gridDim.x * 256;
        for (int e = blockIdx.x * 256 + tid; e < E; e += gsz) {
            int d  = dst[e];
            int rk = atomicAdd(&cnt[d], 1);
            if (rk < 64) pairs[((size_t)d << 6) + rk] = make_int2(srcs[e], e);
        }
    }
}

// Grid-stride prep: zero cnt + build WcatT/bcatI/WoT.
// Cb col order: [0,128)->Q, [128,256)->K, [256,384)->V (natural order).
__global__ __launch_bounds__(256) void prep_kernel(
    const float* __restrict__ Wq, const float* __restrict__ Wk,
    const float* __restrict__ Wv, const float* __restrict__ bq,
    const float* __restrict__ bk, const float* __restrict__ bv,
    const float* __restrict__ Wo,
    ushort* __restrict__ WcatT, float* __restrict__ bcatI, ushort* __restrict__ WoT,
    int* __restrict__ cnt, int N, int GSZ)
{
    const int gid = blockIdx.x * 256 + threadIdx.x;

    for (int i = gid; i < N; i += GSZ) cnt[i] = 0;

    const int WTOT = 384 * 128 + 384 + 128 * 128;
    for (int idx = gid; idx < WTOT; idx += GSZ) {
        if (idx < 384 * 128) {
            int jj = idx >> 7, k = idx & 127;
            const float* W; int c;
            if (jj < 128)      { W = Wq; c = jj; }
            else if (jj < 256) { W = Wk; c = jj - 128; }
            else               { W = Wv; c = jj - 256; }
            WcatT[idx] = f32_to_bf16(W[k * 128 + c]);
        } else if (idx < 384 * 128 + 384) {
            int jj = idx - 384 * 128;
            float b;
            if (jj < 128)      b = bq[jj];
            else if (jj < 256) b = bk[jj - 128];
            else               b = bv[jj - 256];
            bcatI[jj] = b;
        } else {
            int t = idx - (384 * 128 + 384);
            int n = t >> 7, k = t & 127;
            WoT[t] = f32_to_bf16(Wo[k * 128 + n]);
        }
    }
}

// One wave per node, 4 nodes per 256-thread block.
// Layout B: lane = eg*16 + r, r = h*2 + half. 4 edges (eg) per group;
// each lane owns 8 contiguous dims (half) of head h.
// Cb row 640B: Q bf16 at 0, K bf16 at 256, V fp8 at 512 (8B/lane).
// Bucket CSR: edges of node at pairs[node*64 .. node*64+deg), deg<=64.
// 2-stage ping-pong (A = groups 0,8,16,..; B = groups 4,12,20,..).
__global__ __launch_bounds__(256) void attn_kernel(
    const ushort* __restrict__ Cb, const int* __restrict__ deg,
    const int2* __restrict__ pairs, const float* __restrict__ att_bias,
    float* __restrict__ logits_out, ushort* __restrict__ aggb, int N)
{
    const int wv   = threadIdx.x >> 6;
    const int lane = threadIdx.x & 63;
    const int node = blockIdx.x * 4 + wv;
    if (node >= N) return;
    const int eg   = lane >> 4;        // edge-in-group 0..3
    const int r    = lane & 15;        // h*2 + half
    const int h    = r >> 1;
    const int half = lane & 1;

    const char* cb = (const char*)Cb;

    uint4 qw = *((const uint4*)(cb + (size_t)node * 640) + r);
    const float q0 = bf_lo(qw.x), q1 = bf_hi(qw.x);
    const float q2 = bf_lo(qw.y), q3 = bf_hi(qw.y);
    const float q4 = bf_lo(qw.z), q5 = bf_hi(qw.z);
    const float q6 = bf_lo(qw.w), q7 = bf_hi(qw.w);

    const int dg = min(deg[node], 64);

    float l = 0.f;
    float a0 = 0.f, a1 = 0.f, a2 = 0.f, a3 = 0.f;
    float a4 = 0.f, a5 = 0.f, a6 = 0.f, a7 = 0.f;

    if (dg > 0) {
        int gidx = (node << 6) + ((lane < dg) ? lane : (dg - 1));
        int2 se = pairs[gidx];                         // coalesced (src, eid)
        int regSrc = se.x;
        int regEid = se.y;

        uint4 kwA; uint2 vwA; float bbA; int eidA; bool validA;
        uint4 kwB; uint2 vwB; float bbB; int eidB; bool validB = false;

        // prologue: load stage A for g = 0
        {
            int idxr = eg;
            validA = idxr < dg;
            int idxc = validA ? idxr : (dg - 1);
            int srcn = __shfl(regSrc, idxc);
            eidA = __shfl(regEid, idxc);
            const char* kv = cb + (size_t)((uint)srcn * 640u);
            kwA = *((const uint4*)(kv + 256) + r);
            vwA = *((const uint2*)(kv + 512) + r);
            bbA = att_bias[eidA * 8 + h];
        }

        for (int g = 0; g < dg; g += 8) {
            if (g + 4 < dg) {                       // load B(g+4)
                int idxr = g + 4 + eg;
                validB = idxr < dg;
                int idxc = validB ? idxr : (dg - 1);
                int srcn = __shfl(regSrc, idxc);
                eidB = __shfl(regEid, idxc);
                const char* kv = cb + (size_t)((uint)srcn * 640u);
                kwB = *((const uint4*)(kv + 256) + r);
                vwB = *((const uint2*)(kv + 512) + r);
                bbB = att_bias[eidB * 8 + h];
            }
            {                                       // compute A(g)
                float p = q0 * bf_lo(kwA.x) + q1 * bf_hi(kwA.x)
                        + q2 * bf_lo(kwA.y) + q3 * bf_hi(kwA.y)
                        + q4 * bf_lo(kwA.z) + q5 * bf_hi(kwA.z)
                        + q6 * bf_lo(kwA.w) + q7 * bf_hi(kwA.w);
                p += __shfl_xor(p, 1);
                float logit = p * 0.25f + bbA;
                if (validA && half == 0) logits_out[eidA * 8 + h] = logit;
                float pe = validA ? __expf(logit) : 0.f;
                l += pe;
                f32x2 v01 = __builtin_amdgcn_cvt_pk_f32_fp8(vwA.x, false);
                f32x2 v23 = __builtin_amdgcn_cvt_pk_f32_fp8(vwA.x, true);
                f32x2 v45 = __builtin_amdgcn_cvt_pk_f32_fp8(vwA.y, false);
                f32x2 v67 = __builtin_amdgcn_cvt_pk_f32_fp8(vwA.y, true);
                a0 = fmaf(pe, v01[0], a0); a1 = fmaf(pe, v01[1], a1);
                a2 = fmaf(pe, v23[0], a2); a3 = fmaf(pe, v23[1], a3);
                a4 = fmaf(pe, v45[0], a4); a5 = fmaf(pe, v45[1], a5);
                a6 = fmaf(pe, v67[0], a6); a7 = fmaf(pe, v67[1], a7);
            }
            if (g + 8 < dg) {                       // load A(g+8)
                int idxr = g + 8 + eg;
                validA = idxr < dg;
                int idxc = validA ? idxr : (dg - 1);
                int srcn = __shfl(regSrc, idxc);
                eidA = __shfl(regEid, idxc);
                const char* kv = cb + (size_t)((uint)srcn * 640u);
                kwA = *((const uint4*)(kv + 256) + r);
                vwA = *((const uint2*)(kv + 512) + r);
                bbA = att_bias[eidA * 8 + h];
            }
            if (g + 4 < dg) {                       // compute B(g+4)
                float p = q0 * bf_lo(kwB.x) + q1 * bf_hi(kwB.x)
                        + q2 * bf_lo(kwB.y) + q3 * bf_hi(kwB.y)
                        + q4 * bf_lo(kwB.z) + q5 * bf_hi(kwB.z)
                        + q6 * bf_lo(kwB.w) + q7 * bf_hi(kwB.w);
                p += __shfl_xor(p, 1);
                float logit = p * 0.25f + bbB;
                if (validB && half == 0) logits_out[eidB * 8 + h] = logit;
                float pe = validB ? __expf(logit) : 0.f;
                l += pe;
                f32x2 v01 = __builtin_amdgcn_cvt_pk_f32_fp8(vwB.x, false);
                f32x2 v23 = __builtin_amdgcn_cvt_pk_f32_fp8(vwB.x, true);
                f32x2 v45 = __builtin_amdgcn_cvt_pk_f32_fp8(vwB.y, false);
                f32x2 v67 = __builtin_amdgcn_cvt_pk_f32_fp8(vwB.y, true);
                a0 = fmaf(pe, v01[0], a0); a1 = fmaf(pe, v01[1], a1);
                a2 = fmaf(pe, v23[0], a2); a3 = fmaf(pe, v23[1], a3);
                a4 = fmaf(pe, v45[0], a4); a5 = fmaf(pe, v45[1], a5);
                a6 = fmaf(pe, v67[0], a6); a7 = fmaf(pe, v67[1], a7);
            }
        }
    }

    // reduce across eg lanes (bits 4,5); each eg-lane held a disjoint
    // edge subset, so l/aX become full sums per (h, half) lane.
    #pragma unroll
    for (int m = 16; m <= 32; m <<= 1) {
        l  += __shfl_xor(l, m);
        a0 += __shfl_xor(a0, m); a1 += __shfl_xor(a1, m);
        a2 += __shfl_xor(a2, m); a3 += __shfl_xor(a3, m);
        a4 += __shfl_xor(a4, m); a5 += __shfl_xor(a5, m);
        a6 += __shfl_xor(a6, m); a7 += __shfl_xor(a7, m);
    }
    float inv = (l > 0.f) ? (1.f / l) : 0.f;
    if (eg == 0) {
        uint4 o;
        o.x = pack_bf16x2(a0 * inv, a1 * inv);
        o.y = pack_bf16x2(a2 * inv, a3 * inv);
        o.z = pack_bf16x2(a4 * inv, a5 * inv);
        o.w = pack_bf16x2(a6 * inv, a7 * inv);
        ((uint4*)(aggb + (size_t)node * 128))[r] = o;   // cols r*8..r*8+7
    }
}

extern "C" void kernel_launch(void* const* d_in, const int* in_sizes, int n_in,
                              void* d_out, int out_size, void* d_ws, size_t ws_size,
                              hipStream_t stream)
{
    const float* x        = (const float*)d_in[0];
    const int*   ei       = (const int*)d_in[1];   // [2,E]: dst row then src row
    const float* att_bias = (const float*)d_in[2];
    const float* Wq = (const float*)d_in[3];  const float* bq = (const float*)d_in[4];
    const float* Wk = (const float*)d_in[5];  const float* bk = (const float*)d_in[6];
    const float* Wv = (const float*)d_in[7];  const float* bv = (const float*)d_in[8];
    const float* Wo = (const float*)d_in[9];  const float* bo = (const float*)d_in[10];

    const int N = in_sizes[0] / 128;
    const int E = in_sizes[1] / 2;

    float* out    = (float*)d_out;               // [N,128]
    float* logits = out + (size_t)N * 128;       // [E,8]

    char* ws = (char*)d_ws;
    size_t o = 0;
    auto alloc = [&](size_t bytes) -> char* {
        char* p = ws + o;
        o = (o + bytes + 255) & ~(size_t)255;
        return p;
    };
    const int Mpad = ((N + 127) / 128) * 128;
    ushort* Cb    = (ushort*)alloc((size_t)N * 640);       // [Q|K|V fp8] 640B rows
    ushort* aggb  = (ushort*)alloc((size_t)Mpad * 128 * 2);
    ushort* WcatT = (ushort*)alloc((size_t)384 * 128 * 2);
    float*  bcatI = (float*)alloc(384 * 4);
    ushort* WoT   = (ushort*)alloc((size_t)128 * 128 * 2);
    int*    cnt   = (int*)alloc((size_t)N * 4);
    int2*   pairs = (int2*)alloc((size_t)N * 64 * 8);      // bucket CSR

    const int MB = (N + 127) / 128;              // 391
    const int GEMM1_BLOCKS = 1024;               // extra blocks -> scatter tail

    const int PREP_BLOCKS = 512;
    prep_kernel<<<PREP_BLOCKS, 256, 0, stream>>>(
        Wq, Wk, Wv, bq, bk, bv, Wo, WcatT, bcatI, WoT, cnt,
        N, PREP_BLOCKS * 256);

    // QKV projection (blocks < MB) + fused hist+scatter (all 1024 blocks)
    gemm_mfma<0, 3><<<GEMM1_BLOCKS, 256, 0, stream>>>(
        x, WcatT, bcatI, Cb, N, ei, ei + E, cnt, pairs, E);

    attn_kernel<<<(N + 3) / 4, 256, 0, stream>>>(Cb, cnt, pairs, att_bias,
                                                 logits, aggb, N);

    gemm_mfma<1, 1><<<MB, 256, 0, stream>>>(
        aggb, WoT, bo, out, N, nullptr, nullptr, nullptr, nullptr, 0);
}